// Round 6
// baseline (9187.983 us; speedup 1.0000x reference)
//
#include <hip/hip_runtime.h>
#include <math.h>

#define NB 8
#define NN 2048
#define NM 2048
#define NITERS 50

static constexpr float F_EPS  = 0.005f;
static constexpr float LOG2E  = 1.4426950408889634f;
static constexpr float KK     = LOG2E / F_EPS;      // 288.539...
static constexpr float TWOK   = 2.0f * KK;
static constexpr float NEG_LOG2N = -11.0f;          // -log2(2048)

__device__ __forceinline__ float fexp2(float x) { return __builtin_amdgcn_exp2f(x); }
__device__ __forceinline__ float flog2(float x) { return __builtin_amdgcn_logf(x); }

struct SmemT {
    float2 part [16][129];   // [row][partial 0..127], odd pitch
    float2 part2[16][17];    // [row][seg]
    float  wsum[4];
};

// ---------------------------------------------------------------------------
// Contention-free per-batch barrier: 128 WGs/batch, one flag word per WG.
// Arrive: __threadfence (agent release) + RELAXED store of phase to own flag.
// Wait:   wave 0 polls all 128 flags with RELAXED loads (lane l -> flags l,
//         l+64), __all ballot; acquire fence on exit. No RMW, no contention.
// ---------------------------------------------------------------------------
__device__ __forceinline__ void flag_barrier(int* __restrict__ fb, int wgb, int phase)
{
    __syncthreads();
    __threadfence();   // make this WG's prior global writes agent-visible
    if (threadIdx.x == 0)
        __hip_atomic_store(fb + wgb, phase, __ATOMIC_RELAXED, __HIP_MEMORY_SCOPE_AGENT);
    if (threadIdx.x < 64) {
        const int l = threadIdx.x;
        for (;;) {
            const int a = __hip_atomic_load(fb + l,      __ATOMIC_RELAXED, __HIP_MEMORY_SCOPE_AGENT);
            const int c = __hip_atomic_load(fb + l + 64, __ATOMIC_RELAXED, __HIP_MEMORY_SCOPE_AGENT);
            if (__all((a >= phase) && (c >= phase))) break;
            __builtin_amdgcn_s_sleep(2);
        }
        __threadfence();   // acquire: order subsequent reads after flag observation
    }
    __syncthreads();
}

// ---------------------------------------------------------------------------
// Half-sweep for this WG's 16 rows. 4 waves: wave w -> rows [ (w&1)*8, +8 ),
// m-half (w>>1). Each lane: 16 m's (lane + 64*i), reuses each 16B load for
// 8 rows. Streaming chunked LSE; 128 lane-partials/row folded in LDS.
// Math identical to verified R4/R5 (absmax 0.0).
// ---------------------------------------------------------------------------
__device__ __forceinline__ void half_sweep(
    const float4* __restrict__ Pin_b,    // packed opposite side + b*NM
    const float*  __restrict__ Vrow,     // raw points + (b*NN+rowbase)*3
    float4*       __restrict__ Pout_row, // packed out + b*NN + rowbase
    SmemT& sm)
{
    const int tid  = threadIdx.x;
    const int lane = tid & 63;
    const int wave = tid >> 6;
    const int rw   = wave & 1;          // row sub-block (8 rows)
    const int mh   = wave >> 1;         // m half

    float xs0[8], xs1[8], xs2[8];
    {
        const float* vb = Vrow + (size_t)(rw * 8) * 3;
        #pragma unroll
        for (int r = 0; r < 8; ++r) {
            xs0[r] = TWOK * vb[r*3+0];
            xs1[r] = TWOK * vb[r*3+1];
            xs2[r] = TWOK * vb[r*3+2];
        }
    }

    const float4* __restrict__ pp = Pin_b + mh * 1024 + lane;

    float rm[8], rs[8];
    #pragma unroll
    for (int r = 0; r < 8; ++r) { rm[r] = -1e30f; rs[r] = 0.f; }

    for (int ib = 0; ib < 4; ++ib) {
        const float4 p0 = pp[(ib*4 + 0) * 64];
        const float4 p1 = pp[(ib*4 + 1) * 64];
        const float4 p2 = pp[(ib*4 + 2) * 64];
        const float4 p3 = pp[(ib*4 + 3) * 64];
        #pragma unroll
        for (int r = 0; r < 8; ++r) {
            const float z0 = fmaf(xs0[r], p0.x, fmaf(xs1[r], p0.y, fmaf(xs2[r], p0.z, p0.w)));
            const float z1 = fmaf(xs0[r], p1.x, fmaf(xs1[r], p1.y, fmaf(xs2[r], p1.z, p1.w)));
            const float z2 = fmaf(xs0[r], p2.x, fmaf(xs1[r], p2.y, fmaf(xs2[r], p2.z, p2.w)));
            const float z3 = fmaf(xs0[r], p3.x, fmaf(xs1[r], p3.y, fmaf(xs2[r], p3.z, p3.w)));
            const float cm = fmaxf(fmaxf(z0, z1), fmaxf(z2, z3));
            const float nm = fmaxf(rm[r], cm);
            const float s  = (fexp2(z0 - nm) + fexp2(z1 - nm))
                           + (fexp2(z2 - nm) + fexp2(z3 - nm));
            rs[r] = fmaf(rs[r], fexp2(rm[r] - nm), s);
            rm[r] = nm;
        }
    }

    #pragma unroll
    for (int r = 0; r < 8; ++r)
        sm.part[rw*8 + r][mh*64 + lane] = make_float2(rm[r], rs[r]);
    __syncthreads();

    {   // stage 2: 256 threads, each folds 8 of a row's 128 partials
        const int row = tid >> 4, seg = tid & 15;
        float m8 = -1e30f;
        float2 v[8];
        #pragma unroll
        for (int k = 0; k < 8; ++k) { v[k] = sm.part[row][seg*8 + k]; m8 = fmaxf(m8, v[k].x); }
        float s8 = 0.f;
        #pragma unroll
        for (int k = 0; k < 8; ++k) s8 = fmaf(v[k].y, fexp2(v[k].x - m8), s8);
        sm.part2[row][seg] = make_float2(m8, s8);
    }
    __syncthreads();

    if (tid < 16) {   // stage 3: fold 16, write packed output row
        float gm = -1e30f;
        float2 v[16];
        #pragma unroll
        for (int k = 0; k < 16; ++k) { v[k] = sm.part2[tid][k]; gm = fmaxf(gm, v[k].x); }
        float s = 0.f;
        #pragma unroll
        for (int k = 0; k < 16; ++k) s = fmaf(v[k].y, fexp2(v[k].x - gm), s);
        const float lse2 = gm + flog2(s);
        const float* vp = Vrow + (size_t)tid * 3;
        Pout_row[tid] = make_float4(vp[0], vp[1], vp[2], NEG_LOG2N - lse2);
    }
    // no trailing sync needed: next flag_barrier starts with __syncthreads()
}

// ---------------------------------------------------------------------------
// Persistent: pack -> 50x (f-half, bar, g-half, bar) -> final loss.
// grid = 1024 WGs x 256 thr = 4 WG/CU co-resident (launch_bounds(256,4),
// ~19KB LDS) -> 4 waves/SIMD. batch = blockIdx&7 (WGs i,i+256,... on one CU
// share a batch; XCD-local under round-robin — perf only).
// ---------------------------------------------------------------------------
__global__ __launch_bounds__(256, 4) void sinkhorn_persist(
    const float* __restrict__ X, const float* __restrict__ Y,
    float4* __restrict__ Px, float4* __restrict__ Py,
    int* __restrict__ flags, float* __restrict__ out)
{
    __shared__ SmemT sm;
    const int tid     = threadIdx.x;
    const int b       = blockIdx.x & 7;
    const int wgb     = blockIdx.x >> 3;       // 0..127 within batch
    const int rowbase = wgb * 16;
    int* fb = flags + b * 128;

    const float*  Xrow = X + ((size_t)(b * NN + rowbase)) * 3;
    const float*  Yrow = Y + ((size_t)(b * NM + rowbase)) * 3;
    float4* PxRow = Px + b * NN + rowbase;
    float4* PyRow = Py + b * NM + rowbase;
    const float4* PxB = Px + b * NN;
    const float4* PyB = Py + b * NM;

    // pack my 16 rows of Py (dual g = 0)
    if (tid < 16) {
        const float* vp = Yrow + (size_t)tid * 3;
        const float v0 = vp[0], v1 = vp[1], v2 = vp[2];
        const float sq = fmaf(v0, v0, fmaf(v1, v1, v2*v2));
        PyRow[tid] = make_float4(v0, v1, v2, -KK * sq);
    }

    int phase = 1;
    flag_barrier(fb, wgb, phase);

    #pragma unroll 1
    for (int it = 0; it < NITERS; ++it) {
        half_sweep(PyB, Xrow, PxRow, sm);   // f-update
        flag_barrier(fb, wgb, ++phase);
        half_sweep(PxB, Yrow, PyRow, sm);   // g-update
        flag_barrier(fb, wgb, ++phase);
    }

    // final loss over my 16 rows (wave: 8 rows x m-half)
    {
        const int lane = tid & 63;
        const int wave = tid >> 6;
        const int rw   = wave & 1;
        const int mh   = wave >> 1;

        float xr0[8], xr1[8], xr2[8], Af[8], xq[8];
        const float4* xb = PxRow + rw * 8;
        #pragma unroll
        for (int r = 0; r < 8; ++r) {
            const float4 xp = xb[r];
            xr0[r] = xp.x; xr1[r] = xp.y; xr2[r] = xp.z; Af[r] = xp.w;
            xq[r]  = fmaf(xp.x, xp.x, fmaf(xp.y, xp.y, xp.z * xp.z));
        }

        const float4* __restrict__ pp = PyB + mh * 1024 + lane;
        float acc = 0.f;
        for (int i = 0; i < 16; ++i) {
            const float4 p = pp[i * 64];
            const float ysq = fmaf(p.x, p.x, fmaf(p.y, p.y, p.z * p.z));
            #pragma unroll
            for (int r = 0; r < 8; ++r) {
                const float dot = fmaf(xr0[r], p.x, fmaf(xr1[r], p.y, xr2[r] * p.z));
                const float cc  = fmaxf(fmaf(-2.f, dot, xq[r] + ysq), 0.f);
                const float zp  = fmaf(TWOK, dot, Af[r] + p.w);
                acc = fmaf(fexp2(zp), cc, acc);
            }
        }
        #pragma unroll
        for (int o = 32; o > 0; o >>= 1) acc += __shfl_xor(acc, o);
        if (lane == 0) sm.wsum[wave] = acc;
        __syncthreads();
        if (tid == 0) {
            atomicAdd(out, (sm.wsum[0] + sm.wsum[1] + sm.wsum[2] + sm.wsum[3]) * (1.0f / NB));
        }
    }
}

// ---------------------------------------------------------------------------
extern "C" void kernel_launch(void* const* d_in, const int* in_sizes, int n_in,
                              void* d_out, int out_size, void* d_ws, size_t ws_size,
                              hipStream_t stream)
{
    const float* x = (const float*)d_in[0];
    const float* y = (const float*)d_in[1];
    float4* Px = (float4*)d_ws;                       // [B][N] packed x-side
    float4* Py = Px + NB * NN;                        // [B][M] packed y-side
    int*    flags = (int*)((char*)d_ws + (size_t)(NB * NN + NB * NM) * sizeof(float4));

    hipMemsetAsync(flags, 0, NB * 128 * sizeof(int), stream);
    hipMemsetAsync(d_out, 0, sizeof(float), stream);

    sinkhorn_persist<<<NB * NN / 16, 256, 0, stream>>>(x, y, Px, Py, flags, (float*)d_out);
}

// Round 7
// 1119.681 us; speedup vs baseline: 8.2059x; 8.2059x over previous
//
#include <hip/hip_runtime.h>
#include <math.h>

#define NB 8
#define NN 2048
#define NM 2048
#define NITERS 50

static constexpr float F_EPS  = 0.005f;
static constexpr float LOG2E  = 1.4426950408889634f;
static constexpr float KK     = LOG2E / F_EPS;      // 288.539...
static constexpr float TWOK   = 2.0f * KK;
static constexpr float NEG_LOG2N = -11.0f;          // -log2(2048)

__device__ __forceinline__ float fexp2(float x) { return __builtin_amdgcn_exp2f(x); }
__device__ __forceinline__ float flog2(float x) { return __builtin_amdgcn_logf(x); }

// ---------------------------------------------------------------------------
// Pack: P[i] = (v0, v1, v2, K*(dual - |v|^2)) with dual = 0.
// ---------------------------------------------------------------------------
__global__ void pack_init(const float* __restrict__ V, float4* __restrict__ Pout, int total)
{
    int i = blockIdx.x * blockDim.x + threadIdx.x;
    if (i < total) {
        float v0 = V[3*i], v1 = V[3*i+1], v2 = V[3*i+2];
        float s  = fmaf(v0, v0, fmaf(v1, v1, v2*v2));
        Pout[i]  = make_float4(v0, v1, v2, -KK * s);
    }
}

// ---------------------------------------------------------------------------
// Sinkhorn half-sweep. Geometry for latency hiding:
//   grid = B*N/16 = 1024 WGs x 256 thr; launch_bounds(256,4) -> 4 WG/CU
//   (4 waves/SIMD). Wave w: rows [8*(w&1), +8), m-half (w>>1).
//   Per lane: 16 m's (mh*1024 + i*64 + lane), each 16B load reused for 8
//   rows; register double-buffer prefetch of next 4 loads hides L2 latency.
//   Streaming chunk-4 LSE (math identical to verified absmax-0.0 kernels).
//   LDS combine remapped conflict-free: stage2 thread = (row=tid&15,
//   seg=tid>>4) so 16 consecutive lanes hit 16 distinct banks.
// ---------------------------------------------------------------------------
__global__ __launch_bounds__(256, 4) void sink_update(
    const float4* __restrict__ Pin,   // [B][M] packed opposite side
    const float*  __restrict__ Vraw,  // [B][N][3] raw points of side being updated
    float4*       __restrict__ Pout)  // [B][N] packed output
{
    __shared__ float2 part [16][129];  // [row][partial 0..127]
    __shared__ float2 part2[16][17];   // [row][seg 0..15]
    const int tid  = threadIdx.x;
    const int lane = tid & 63;
    const int wave = tid >> 6;
    const int rw   = wave & 1;          // row sub-block (8 rows)
    const int mh   = wave >> 1;         // m half
    const int wgs_per_b = NN / 16;      // 128
    const int b       = blockIdx.x / wgs_per_b;
    const int rowbase = (blockIdx.x % wgs_per_b) * 16;

    float xs0[8], xs1[8], xs2[8];
    {
        const float* vb = Vraw + ((size_t)(b * NN + rowbase + rw * 8)) * 3;
        #pragma unroll
        for (int r = 0; r < 8; ++r) {
            xs0[r] = TWOK * vb[r*3+0];
            xs1[r] = TWOK * vb[r*3+1];
            xs2[r] = TWOK * vb[r*3+2];
        }
    }

    const float4* __restrict__ pp = Pin + b * NM + mh * 1024 + lane;

    float rm[8], rs[8];
    #pragma unroll
    for (int r = 0; r < 8; ++r) { rm[r] = -1e30f; rs[r] = 0.f; }

    float4 c0 = pp[0*64], c1 = pp[1*64], c2 = pp[2*64], c3 = pp[3*64];

    #pragma unroll
    for (int ib = 0; ib < 4; ++ib) {
        float4 n0, n1, n2, n3;
        if (ib < 3) {                       // prefetch next chunk
            n0 = pp[(ib*4 + 4) * 64];
            n1 = pp[(ib*4 + 5) * 64];
            n2 = pp[(ib*4 + 6) * 64];
            n3 = pp[(ib*4 + 7) * 64];
        }
        #pragma unroll
        for (int r = 0; r < 8; ++r) {
            const float z0 = fmaf(xs0[r], c0.x, fmaf(xs1[r], c0.y, fmaf(xs2[r], c0.z, c0.w)));
            const float z1 = fmaf(xs0[r], c1.x, fmaf(xs1[r], c1.y, fmaf(xs2[r], c1.z, c1.w)));
            const float z2 = fmaf(xs0[r], c2.x, fmaf(xs1[r], c2.y, fmaf(xs2[r], c2.z, c2.w)));
            const float z3 = fmaf(xs0[r], c3.x, fmaf(xs1[r], c3.y, fmaf(xs2[r], c3.z, c3.w)));
            const float cm = fmaxf(fmaxf(z0, z1), fmaxf(z2, z3));
            const float nm = fmaxf(rm[r], cm);
            const float s  = (fexp2(z0 - nm) + fexp2(z1 - nm))
                           + (fexp2(z2 - nm) + fexp2(z3 - nm));
            rs[r] = fmaf(rs[r], fexp2(rm[r] - nm), s);
            rm[r] = nm;
        }
        if (ib < 3) { c0 = n0; c1 = n1; c2 = n2; c3 = n3; }
    }

    #pragma unroll
    for (int r = 0; r < 8; ++r)
        part[rw*8 + r][mh*64 + lane] = make_float2(rm[r], rs[r]);
    __syncthreads();

    {   // stage 2: thread (row=tid&15, seg=tid>>4) folds 8 partials — 16
        // consecutive lanes read 16 distinct rows -> distinct banks.
        const int row = tid & 15, seg = tid >> 4;
        float m8 = -1e30f;
        float2 v[8];
        #pragma unroll
        for (int k = 0; k < 8; ++k) { v[k] = part[row][seg*8 + k]; m8 = fmaxf(m8, v[k].x); }
        float s8 = 0.f;
        #pragma unroll
        for (int k = 0; k < 8; ++k) s8 = fmaf(v[k].y, fexp2(v[k].x - m8), s8);
        part2[row][seg] = make_float2(m8, s8);
    }
    __syncthreads();

    if (tid < 16) {   // stage 3: fold 16 segs, write packed output row
        float gm = -1e30f;
        float2 v[16];
        #pragma unroll
        for (int k = 0; k < 16; ++k) { v[k] = part2[tid][k]; gm = fmaxf(gm, v[k].x); }
        float s = 0.f;
        #pragma unroll
        for (int k = 0; k < 16; ++k) s = fmaf(v[k].y, fexp2(v[k].x - gm), s);
        const float lse2 = gm + flog2(s);
        const int n0 = rowbase + tid;
        const float* vp = Vraw + ((size_t)(b * NN + n0)) * 3;
        Pout[b * NN + n0] = make_float4(vp[0], vp[1], vp[2], NEG_LOG2N - lse2);
    }
}

// ---------------------------------------------------------------------------
// Final loss, same geometry + prefetch.
// out = (1/B) * sum P*C, P = exp2(Af + Ag + 2K*dot), C = max(|x|^2+|y|^2-2dot,0)
// ---------------------------------------------------------------------------
__global__ __launch_bounds__(256, 4) void final_loss(
    const float4* __restrict__ Px, const float4* __restrict__ Py,
    float* __restrict__ out)
{
    __shared__ float wsum[4];
    const int tid  = threadIdx.x;
    const int lane = tid & 63;
    const int wave = tid >> 6;
    const int rw   = wave & 1;
    const int mh   = wave >> 1;
    const int wgs_per_b = NN / 16;
    const int b       = blockIdx.x / wgs_per_b;
    const int rowbase = (blockIdx.x % wgs_per_b) * 16;

    float xr0[8], xr1[8], xr2[8], Af[8], xq[8];
    {
        const float4* xb = Px + b * NN + rowbase + rw * 8;
        #pragma unroll
        for (int r = 0; r < 8; ++r) {
            const float4 xp = xb[r];
            xr0[r] = xp.x; xr1[r] = xp.y; xr2[r] = xp.z; Af[r] = xp.w;
            xq[r]  = fmaf(xp.x, xp.x, fmaf(xp.y, xp.y, xp.z * xp.z));
        }
    }

    const float4* __restrict__ pp = Py + b * NM + mh * 1024 + lane;

    float acc = 0.f;
    float4 cur = pp[0];
    #pragma unroll
    for (int i = 0; i < 16; ++i) {
        float4 nxt;
        if (i < 15) nxt = pp[(i + 1) * 64];
        const float ysq = fmaf(cur.x, cur.x, fmaf(cur.y, cur.y, cur.z * cur.z));
        #pragma unroll
        for (int r = 0; r < 8; ++r) {
            const float dot = fmaf(xr0[r], cur.x, fmaf(xr1[r], cur.y, xr2[r] * cur.z));
            const float cc  = fmaxf(fmaf(-2.f, dot, xq[r] + ysq), 0.f);
            const float zp  = fmaf(TWOK, dot, Af[r] + cur.w);
            acc = fmaf(fexp2(zp), cc, acc);
        }
        if (i < 15) cur = nxt;
    }
    #pragma unroll
    for (int o = 32; o > 0; o >>= 1) acc += __shfl_xor(acc, o);
    if (lane == 0) wsum[wave] = acc;
    __syncthreads();
    if (tid == 0) {
        atomicAdd(out, (wsum[0] + wsum[1] + wsum[2] + wsum[3]) * (1.0f / NB));
    }
}

// ---------------------------------------------------------------------------
extern "C" void kernel_launch(void* const* d_in, const int* in_sizes, int n_in,
                              void* d_out, int out_size, void* d_ws, size_t ws_size,
                              hipStream_t stream)
{
    const float* x = (const float*)d_in[0];
    const float* y = (const float*)d_in[1];
    float4* Px = (float4*)d_ws;            // [B][N] packed x-side
    float4* Py = Px + NB * NN;             // [B][M] packed y-side

    pack_init<<<(NB * NM + 255) / 256, 256, 0, stream>>>(y, Py, NB * NM);

    for (int it = 0; it < NITERS; ++it) {
        sink_update<<<NB * NN / 16, 256, 0, stream>>>(Py, x, Px);  // f-update
        sink_update<<<NB * NM / 16, 256, 0, stream>>>(Px, y, Py);  // g-update
    }

    hipMemsetAsync(d_out, 0, sizeof(float), stream);
    final_loss<<<NB * NN / 16, 256, 0, stream>>>(Px, Py, (float*)d_out);
}